// Round 12
// baseline (375.823 us; speedup 1.0000x reference)
//
#include <hip/hip_runtime.h>
#include <hip/hip_bf16.h>
#include <math.h>

#define NTOK 8192
#define DM 512
#define DFF 2048
#define NE 8
#define ROWCAP 33792   // 32768 assignments max + 8*128 granule padding

typedef __attribute__((ext_vector_type(8))) short bfrag;
typedef __attribute__((ext_vector_type(4))) float f32x4;
typedef __attribute__((ext_vector_type(4))) unsigned int u32x4;
typedef __attribute__((ext_vector_type(4))) short s16x4;

// async global->LDS, 16B/lane; LDS dest = wave-uniform base + lane*16 (global addr may be per-lane)
#define GLD_LDS16(gp, lp) __builtin_amdgcn_global_load_lds( \
    (const __attribute__((address_space(1))) void*)(gp),    \
    (__attribute__((address_space(3))) void*)(lp), 16, 0, 0)

// LDS byte offset of a generic pointer known to point into LDS
#define LDS_OFF(p) ((unsigned)(size_t)(__attribute__((address_space(3))) void*)(p))

// workgroup barrier WITHOUT an implicit vmcnt(0) drain (keeps global_load_lds prefetches
// in flight) but WITH lgkmcnt(0): ISA requires draining LDS ops before s_barrier when
// other waves will read the data (epilogue ds_write -> cross-wave read). In the K-loop
// this is a no-op (ds_reads are drained before MFMA; DMA counts in vmcnt only).
__device__ __forceinline__ void wg_barrier() {
  asm volatile("" ::: "memory");
  __builtin_amdgcn_sched_barrier(0);
  asm volatile("s_waitcnt lgkmcnt(0)" ::: "memory");
  __builtin_amdgcn_s_barrier();
  __builtin_amdgcn_sched_barrier(0);
  asm volatile("" ::: "memory");
}

// inline-asm ds_read_b128 with compile-time literal offset: invisible to the compiler's
// waitcnt pass (no implicit vmcnt(0) drain vs pending global_load_lds DMA), and the
// literal offset removes per-read VALU address adds.
// Caller MUST fence with s_waitcnt lgkmcnt(N) + sched_barrier(0) before consuming.
#define LDS_READ_OFF(dst, base, LIT) \
  asm volatile("ds_read_b128 %0, %1 offset:" LIT : "=v"(dst) : "v"(base))

__device__ __forceinline__ short f2bf(float f) {
  unsigned u = __builtin_bit_cast(unsigned, f);
  u += 0x7fffu + ((u >> 16) & 1u);
  return (short)(u >> 16);
}
__device__ __forceinline__ float bf2f(short s) {
  unsigned u = ((unsigned)(unsigned short)s) << 16;
  return __builtin_bit_cast(float, u);
}
// tanh-form GELU via hw exp2+rcp (~7 ops). max |diff vs erf-gelu| ~5e-4.
__device__ __forceinline__ float fast_gelu(float v) {
  float u = fmaf(v * v * v, 0.044715f, v) * 0.7978845608f;
  float ex = __builtin_amdgcn_exp2f(u * -2.8853900818f);
  return v * __builtin_amdgcn_rcpf(1.f + ex);
}

// ---------------- fp32 -> bf16 transpose-convert, W1 & W2 in ONE launch ----------------
// 64(rows) x 32(cols) input tiles: output rows are (c0+oc) with 64 shorts = 128 B = one
// full cache line per row (8 threads x 16B bfrag stores). Loads stay 128 B segments.
__global__ __launch_bounds__(256) void cvtT2_kernel(const float* __restrict__ W1,
                                                    short* __restrict__ o1,
                                                    const float* __restrict__ W2,
                                                    short* __restrict__ o2) {
  __shared__ float t[64][33];
  int z = blockIdx.y;
  const float* in; short* o; int R, C, r0, c0;
  if (z < NE) {
    in = W1 + (size_t)z * DM * DFF; o = o1 + (size_t)z * DM * DFF; R = DM; C = DFF;
    r0 = (blockIdx.x & 7) * 64; c0 = (blockIdx.x >> 3) * 32;        // 8 x 64 tiles
  } else {
    z -= NE;
    in = W2 + (size_t)z * DFF * DM; o = o2 + (size_t)z * DFF * DM; R = DFF; C = DM;
    r0 = (blockIdx.x & 31) * 64; c0 = (blockIdx.x >> 5) * 32;       // 32 x 16 tiles
  }
  int tx = threadIdx.x & 31, ty = threadIdx.x >> 5;   // ty 0..7
  #pragma unroll
  for (int i = 0; i < 64; i += 8)
    t[ty + i][tx] = in[(size_t)(r0 + ty + i) * C + c0 + tx];
  __syncthreads();
  int tseg = threadIdx.x & 7, oc = threadIdx.x >> 3;  // oc 0..31
  bfrag v;
  #pragma unroll
  for (int jj = 0; jj < 8; jj++) v[jj] = f2bf(t[tseg * 8 + jj][oc]);
  *(bfrag*)(o + (size_t)(c0 + oc) * R + r0 + tseg * 8) = v;
}

// ---------------- router (fused: also emits xb = bf16(x)) ----------------
__global__ __launch_bounds__(256) void router_kernel(const float* __restrict__ x,
                                                     const float* __restrict__ rw,
                                                     short* __restrict__ xb,
                                                     int* __restrict__ sel_e,
                                                     float* __restrict__ sel_w,
                                                     float* __restrict__ part) {
  __shared__ float s_cnt[NE], s_ps[NE];
  int tid = threadIdx.x;
  if (tid < NE) { s_cnt[tid] = 0.f; s_ps[tid] = 0.f; }
  __syncthreads();
  int wave = tid >> 6, lane = tid & 63;
  float myc[NE], myp[NE];
  #pragma unroll
  for (int e = 0; e < NE; e++) { myc[e] = 0.f; myp[e] = 0.f; }

  for (int i = 0; i < 8; i++) {
    int token = blockIdx.x * 32 + wave * 8 + i;
    const float* xt = x + (size_t)token * DM;
    float acc[NE];
    #pragma unroll
    for (int e = 0; e < NE; e++) acc[e] = 0.f;
    #pragma unroll
    for (int kk = 0; kk < DM / 64; kk++) {
      int k = kk * 64 + lane;
      float xv = xt[k];
      xb[(size_t)token * DM + k] = f2bf(xv);   // fused fp32->bf16 emit
      f32x4 r0 = *(const f32x4*)(rw + k * NE);
      f32x4 r1 = *(const f32x4*)(rw + k * NE + 4);
      acc[0] += xv * r0[0]; acc[1] += xv * r0[1]; acc[2] += xv * r0[2]; acc[3] += xv * r0[3];
      acc[4] += xv * r1[0]; acc[5] += xv * r1[1]; acc[6] += xv * r1[2]; acc[7] += xv * r1[3];
    }
    #pragma unroll
    for (int off = 32; off >= 1; off >>= 1) {
      #pragma unroll
      for (int e = 0; e < NE; e++) acc[e] += __shfl_xor(acc[e], off, 64);
    }
    float mx = acc[0];
    #pragma unroll
    for (int e = 1; e < NE; e++) mx = fmaxf(mx, acc[e]);
    float p[NE]; float sum = 0.f;
    #pragma unroll
    for (int e = 0; e < NE; e++) { p[e] = expf(acc[e] - mx); sum += p[e]; }
    float inv = 1.f / sum;
    #pragma unroll
    for (int e = 0; e < NE; e++) p[e] *= inv;
    float sp[4]; int si[4]; unsigned used = 0;
    #pragma unroll
    for (int s = 0; s < 4; s++) {
      float bp = -1.f; int bi = 0;
      #pragma unroll
      for (int e = 0; e < NE; e++)
        if (!((used >> e) & 1u) && p[e] > bp) { bp = p[e]; bi = e; }
      used |= 1u << bi; sp[s] = bp; si[s] = bi;
    }
    float csum = 0.f, wsum = 0.f; bool keep[4];
    #pragma unroll
    for (int s = 0; s < 4; s++) {
      keep[s] = (s < 1) || (csum < 0.9f);
      csum += sp[s];
      if (keep[s]) wsum += sp[s];
    }
    wsum = fmaxf(wsum, 1e-9f);
    if (lane == 0) {
      #pragma unroll
      for (int s = 0; s < 4; s++) {
        sel_e[token * 4 + s] = keep[s] ? si[s] : -1;
        sel_w[token * 4 + s] = keep[s] ? sp[s] / wsum : 0.f;
      }
      #pragma unroll
      for (int e = 0; e < NE; e++) myp[e] += p[e];
      #pragma unroll
      for (int s = 0; s < 4; s++) if (keep[s]) myc[si[s]] += 1.f;
    }
  }
  if (lane == 0) {
    #pragma unroll
    for (int e = 0; e < NE; e++) { atomicAdd(&s_cnt[e], myc[e]); atomicAdd(&s_ps[e], myp[e]); }
  }
  __syncthreads();
  if (tid < NE) {
    part[blockIdx.x * 16 + tid] = s_cnt[tid];
    part[blockIdx.x * 16 + 8 + tid] = s_ps[tid];
  }
}

// ---------------- prep: aux scalar + expert bases (128-aligned), parallel reduce ----------------
__global__ __launch_bounds__(256) void prep_kernel(const float* __restrict__ part,
                                                   float* __restrict__ auxp,
                                                   int* __restrict__ meta) {
  __shared__ float red2[16][16];   // [group][idx]
  __shared__ float red[16];
  int tid = threadIdx.x;
  int idx = tid & 15, g = tid >> 4;      // 16 groups, each sums 16 router blocks
  float s = 0.f;
  #pragma unroll
  for (int b = 0; b < 16; b++) s += part[(g * 16 + b) * 16 + idx];
  red2[g][idx] = s;
  __syncthreads();
  if (tid < 16) {
    float t = 0.f;
    #pragma unroll
    for (int g2 = 0; g2 < 16; g2++) t += red2[g2][tid];
    red[tid] = t;
  }
  __syncthreads();
  if (tid == 0) {
    float tot = 0.f;
    for (int e = 0; e < NE; e++) tot += red[e];
    float t = fmaxf(tot, 1.f), s2 = 0.f;
    for (int e = 0; e < NE; e++) s2 += (red[e] / t) * (red[NE + e] / (float)NTOK);
    auxp[0] = 0.01f * (float)NE * s2;
    int off = 0;
    for (int e = 0; e < NE; e++) {
      int c = (int)(red[e] + 0.5f);
      meta[e] = c; meta[8 + e] = off;
      off += (c + 127) & ~127;   // 128-granule padding (M-tile = 128)
    }
  }
  if (tid < NE) meta[16 + tid] = 0;
}

// ---------------- build compact assignment lists ----------------
__global__ __launch_bounds__(256) void build_kernel(const int* __restrict__ sel_e,
                                                    const float* __restrict__ sel_w,
                                                    int* __restrict__ meta,
                                                    int* __restrict__ mlist,
                                                    float* __restrict__ wrow,
                                                    int* __restrict__ arow) {
  __shared__ int lcnt[NE], roff[NE];
  int tid = threadIdx.x;
  if (tid < NE) lcnt[tid] = 0;
  __syncthreads();
  int t = blockIdx.x * 32 + tid;
  int slots[4], es[4];
  bool active = tid < 32;
  if (active) {
    #pragma unroll
    for (int s = 0; s < 4; s++) {
      es[s] = sel_e[t * 4 + s];
      slots[s] = (es[s] >= 0) ? atomicAdd(&lcnt[es[s]], 1) : -1;
    }
  }
  __syncthreads();
  if (tid < NE) roff[tid] = atomicAdd(&meta[16 + tid], lcnt[tid]);
  __syncthreads();
  if (active) {
    #pragma unroll
    for (int s = 0; s < 4; s++) {
      int e = es[s];
      if (e >= 0) {
        int hrow = meta[8 + e] + roff[e] + slots[s];
        mlist[hrow] = t;
        wrow[hrow] = sel_w[t * 4 + s];
        arow[t * 4 + s] = hrow;
      } else {
        arow[t * 4 + s] = -1;
      }
    }
  }
}

// ---------------- sparse GEMM1, 128x128 tile, BK=64, counted-vmcnt + asm ds_read ----------------
// R11-verified base (106.9 us) + ks-split pipeline: issue ALL 16 ds_reads (ks0 then ks1),
// wait lgkmcnt(8) -> MFMA ks0 (ks1's reads drain underneath), wait lgkmcnt(0) -> MFMA ks1.
// LDS ops complete in order, so lgkmcnt(8) == "oldest 8 (ks0) done". Pattern ran correct
// on-silicon in R5. Live asm outputs 16x4=64 VGPR + acc 64 -> ~155 total, far from spill.
__global__ __launch_bounds__(256, 2) void gemm1_sp(const short* __restrict__ A,
                                                   const short* __restrict__ W1t,
                                                   const float* __restrict__ b1,
                                                   short* __restrict__ H,
                                                   const int* __restrict__ mlist,
                                                   const int* __restrict__ meta) {
  __shared__ __align__(16) short smem[32768];   // 64 KB: As | Bs, reused as Hs in epilogue
  short* As = smem;
  short* Bs = smem + 16384;
  unsigned nwg = gridDim.x * gridDim.y;                        // 8192
  unsigned hid = blockIdx.y * gridDim.x + blockIdx.x;
  unsigned lid = (hid & 7) * (nwg >> 3) + (hid >> 3);          // chunked XCD swizzle
  int xblk = lid & 15, yblk = lid >> 4;                        // gridDim.x == 16
  int e = yblk >> 6, j = yblk & 63;
  int cnt = meta[e];
  if (j * 128 >= cnt) return;
  int base = meta[8 + e];
  int tid = threadIdx.x, wave = tid >> 6, lane = tid & 63;
  int wm = wave >> 1, wn = wave & 1, quad = lane >> 4, l16 = lane & 15;
  int n0 = xblk * 128;
  const short* Bt = W1t + (size_t)e * DFF * DM;

  // staging: chunk c = q*256 + tid; row r = c>>3; logical slot s = (c&7)^(r&7) at source
  const short* agp[4]; const short* bgp[4];
  #pragma unroll
  for (int q = 0; q < 4; q++) {
    int c = q * 256 + tid;
    int r = c >> 3, s = (c & 7) ^ (r & 7);
    int rl = j * 128 + r;
    int tok = mlist[base + (rl < cnt ? rl : cnt - 1)];
    agp[q] = A + (size_t)tok * DM + s * 8;
    bgp[q] = Bt + (size_t)(n0 + r) * DM + s * 8;
  }

  f32x4 acc[4][4];
  #pragma unroll
  for (int i = 0; i < 4; i++)
    #pragma unroll
    for (int jj = 0; jj < 4; jj++) acc[i][jj] = (f32x4){0.f, 0.f, 0.f, 0.f};

  auto stage = [&](int bsel, int kt) {
    short* Ab = As + bsel * 8192 + wave * 512;
    short* Bb = Bs + bsel * 8192 + wave * 512;
    #pragma unroll
    for (int q = 0; q < 4; q++) {
      GLD_LDS16(agp[q] + kt, Ab + q * 2048);
      GLD_LDS16(bgp[q] + kt, Bb + q * 2048);
    }
  };

  stage(0, 0);
  stage(1, 64);

  // per-thread read bases (row stride 128 B); fragment rows differ by literal 2048 B
  unsigned aAddr0 = LDS_OFF(As) + (wm * 64 + l16) * 128;
  unsigned bAddr0 = LDS_OFF(Bs) + (wn * 64 + l16) * 128;
  unsigned soB[2];
  #pragma unroll
  for (int ks = 0; ks < 2; ks++) soB[ks] = (unsigned)((((ks << 2) | quad) ^ (l16 & 7)) << 4);

  const int NT = DM / 64;   // 8
  for (int t = 0; t < NT; t++) {
    if (t + 1 < NT) asm volatile("s_waitcnt vmcnt(8)" ::: "memory");
    else            asm volatile("s_waitcnt vmcnt(0)" ::: "memory");
    wg_barrier();              // tile t visible to all waves
    unsigned bo = (unsigned)((t & 1) * 16384);
    unsigned aB0 = aAddr0 + bo + soB[0], bB0 = bAddr0 + bo + soB[0];
    unsigned aB1 = aAddr0 + bo + soB[1], bB1 = bAddr0 + bo + soB[1];
    bfrag a0[4], b0[4], a1[4], b1f[4];
    LDS_READ_OFF(a0[0], aB0, "0");    LDS_READ_OFF(a0[1], aB0, "2048");
    LDS_READ_OFF(a0[2], aB0, "4096"); LDS_READ_OFF(a0[3], aB0, "6144");
    LDS_READ_OFF(b0[0], bB0, "0");    LDS_READ_OFF(b0[1], bB0, "2048");
    LDS_READ_OFF(b0[2], bB0, "4096"); LDS_READ_OFF(b0[3], bB0, "6144");
    LDS_READ_OFF(a1[0], aB1, "0");    LDS_READ_OFF(a1[1], aB1, "2048");
    LDS_READ_OFF(a1[2], aB1, "4096"); LDS_READ_OFF(a1[3], aB1, "6144");
    LDS_READ_OFF(b1f[0], bB1, "0");    LDS_READ_OFF(b1f[1], bB1, "2048");
    LDS_READ_OFF(b1f[2], bB1, "4096"); LDS_READ_OFF(b1f[3], bB1, "6144");
    asm volatile("s_waitcnt lgkmcnt(8)" ::: "memory");   // ks0's 8 (oldest) complete
    __builtin_amdgcn_sched_barrier(0);
    __builtin_amdgcn_s_setprio(1);
    #pragma unroll
    for (int mi = 0; mi < 4; mi++)
      #pragma unroll
      for (int ni = 0; ni < 4; ni++)
        acc[mi][ni] = __builtin_amdgcn_mfma_f32_16x16x32_bf16(a0[mi], b0[ni], acc[mi][ni], 0, 0, 0);
    __builtin_amdgcn_s_setprio(0);
    asm volatile("s_waitcnt lgkmcnt(0)" ::: "memory");   // ks1 drained under ks0's MFMA
    __builtin_amdgcn_sched_barrier(0);
    __builtin_amdgcn_s_setprio(1);
    #pragma unroll
    for (int mi = 0; mi < 4; mi++)
      #pragma unroll
      for (int ni = 0; ni < 4; ni++)
        acc[mi][ni] = __builtin_amdgcn_mfma_f32_16x16x32_bf16(a1[mi], b1f[ni], acc[mi][ni], 0, 0, 0);
    __builtin_amdgcn_s_setprio(0);
    wg_barrier();              // all waves done reading buf[t&1]
    if (t + 2 < NT) stage(t & 1, (t + 2) * 64);   // overwrite just-vacated buffer
  }

  // epilogue: gelu+bias -> LDS tile -> coalesced 16B stores
  short (*Hs)[136] = (short(*)[136])smem;   // 128*136*2 = 34816 B, LDS idle after loop
  const float* bb = b1 + (size_t)e * DFF;
  #pragma unroll
  for (int mi = 0; mi < 4; mi++) {
    int rl = wm * 64 + mi * 16 + quad * 4;
    #pragma unroll
    for (int ni = 0; ni < 4; ni++) {
      int cl = wn * 64 + ni * 16 + l16;
      float bv = bb[n0 + cl];
      #pragma unroll
      for (int r = 0; r < 4; r++)
        Hs[rl + r][cl] = f2bf(fast_gelu(acc[mi][ni][r] + bv));
    }
  }
  wg_barrier();
  int rbase0 = base + j * 128;
  int row16 = tid >> 4, colg = (tid & 15) * 8;
  #pragma unroll
  for (int ps = 0; ps < 8; ps++) {
    int row = ps * 16 + row16;
    u32x4 v = *(const u32x4*)&Hs[row][colg];
    *(u32x4*)(H + (size_t)(rbase0 + row) * DFF + n0 + colg) = v;
  }
}

// ---------------- sparse GEMM2, same structure, K=DFF ----------------
__global__ __launch_bounds__(256, 2) void gemm2_sp(const short* __restrict__ H,
                                                   const short* __restrict__ W2t,
                                                   const float* __restrict__ b2,
                                                   short* __restrict__ partial,
                                                   const float* __restrict__ wrow,
                                                   const int* __restrict__ meta) {
  __shared__ __align__(16) short smem[32768];
  short* As = smem;
  short* Bs = smem + 16384;
  unsigned nwg = gridDim.x * gridDim.y;                        // 2048
  unsigned hid = blockIdx.y * gridDim.x + blockIdx.x;
  unsigned lid = (hid & 7) * (nwg >> 3) + (hid >> 3);          // chunked XCD swizzle
  int xblk = lid & 3, yblk = lid >> 2;                         // gridDim.x == 4
  int e = yblk >> 6, j = yblk & 63;
  int cnt = meta[e];
  if (j * 128 >= cnt) return;
  int base = meta[8 + e];
  int tid = threadIdx.x, wave = tid >> 6, lane = tid & 63;
  int wm = wave >> 1, wn = wave & 1, quad = lane >> 4, l16 = lane & 15;
  int n0 = xblk * 128;
  const short* Bt = W2t + (size_t)e * DM * DFF;

  const short* agp[4]; const short* bgp[4];
  #pragma unroll
  for (int q = 0; q < 4; q++) {
    int c = q * 256 + tid;
    int r = c >> 3, s = (c & 7) ^ (r & 7);
    agp[q] = H + (size_t)(base + j * 128 + r) * DFF + s * 8;
    bgp[q] = Bt + (size_t)(n0 + r) * DFF + s * 8;
  }

  f32x4 acc[4][4];
  #pragma unroll
  for (int i = 0; i < 4; i++)
    #pragma unroll
    for (int jj = 0; jj < 4; jj++) acc[i][jj] = (f32x4){0.f, 0.f, 0.f, 0.f};

  auto stage = [&](int bsel, int kt) {
    short* Ab = As + bsel * 8192 + wave * 512;
    short* Bb = Bs + bsel * 8192 + wave * 512;
    #pragma unroll
    for (int q = 0; q < 4; q++) {
      GLD_LDS16(agp[q] + kt, Ab + q * 2048);
      GLD_LDS16(bgp[q] + kt, Bb + q * 2048);
    }
  };

  stage(0, 0);
  stage(1, 64);

  unsigned aAddr0 = LDS_OFF(As) + (wm * 64 + l16) * 128;
  unsigned bAddr0 = LDS_OFF(Bs) + (wn * 64 + l16) * 128;
  unsigned soB[2];
  #pragma unroll
  for (int ks = 0; ks < 2; ks++) soB[ks] = (unsigned)((((ks << 2) | quad) ^ (l16 & 7)) << 4);

  const int NT = DFF / 64;  // 32
  for (int t = 0; t < NT; t++) {
    if (t + 1 < NT) asm volatile("s_waitcnt vmcnt(8)" ::: "memory");
    else            asm volatile("s_waitcnt vmcnt(0)" ::: "memory");
    wg_barrier();
    unsigned bo = (unsigned)((t & 1) * 16384);
    unsigned aB0 = aAddr0 + bo + soB[0], bB0 = bAddr0 + bo + soB[0];
    unsigned aB1 = aAddr0 + bo + soB[1], bB1 = bAddr0 + bo + soB[1];
    bfrag a0[4], b0[4], a1[4], b1f[4];
    LDS_READ_OFF(a0[0], aB0, "0");    LDS_READ_OFF(a0[1], aB0, "2048");
    LDS_READ_OFF(a0[2], aB0, "4096"); LDS_READ_OFF(a0[3], aB0, "6144");
    LDS_READ_OFF(b0[0], bB0, "0");    LDS_READ_OFF(b0[1], bB0, "2048");
    LDS_READ_OFF(b0[2], bB0, "4096"); LDS_READ_OFF(b0[3], bB0, "6144");
    LDS_READ_OFF(a1[0], aB1, "0");    LDS_READ_OFF(a1[1], aB1, "2048");
    LDS_READ_OFF(a1[2], aB1, "4096"); LDS_READ_OFF(a1[3], aB1, "6144");
    LDS_READ_OFF(b1f[0], bB1, "0");    LDS_READ_OFF(b1f[1], bB1, "2048");
    LDS_READ_OFF(b1f[2], bB1, "4096"); LDS_READ_OFF(b1f[3], bB1, "6144");
    asm volatile("s_waitcnt lgkmcnt(8)" ::: "memory");
    __builtin_amdgcn_sched_barrier(0);
    __builtin_amdgcn_s_setprio(1);
    #pragma unroll
    for (int mi = 0; mi < 4; mi++)
      #pragma unroll
      for (int ni = 0; ni < 4; ni++)
        acc[mi][ni] = __builtin_amdgcn_mfma_f32_16x16x32_bf16(a0[mi], b0[ni], acc[mi][ni], 0, 0, 0);
    __builtin_amdgcn_s_setprio(0);
    asm volatile("s_waitcnt lgkmcnt(0)" ::: "memory");
    __builtin_amdgcn_sched_barrier(0);
    __builtin_amdgcn_s_setprio(1);
    #pragma unroll
    for (int mi = 0; mi < 4; mi++)
      #pragma unroll
      for (int ni = 0; ni < 4; ni++)
        acc[mi][ni] = __builtin_amdgcn_mfma_f32_16x16x32_bf16(a1[mi], b1f[ni], acc[mi][ni], 0, 0, 0);
    __builtin_amdgcn_s_setprio(0);
    wg_barrier();
    if (t + 2 < NT) stage(t & 1, (t + 2) * 64);
  }

  // epilogue: w*(acc+bias) -> LDS tile -> coalesced 16B stores
  short (*Hs)[136] = (short(*)[136])smem;
  const float* bb = b2 + (size_t)e * DM;
  int rbase0 = base + j * 128;
  #pragma unroll
  for (int mi = 0; mi < 4; mi++) {
    int rl = wm * 64 + mi * 16 + quad * 4;
    #pragma unroll
    for (int ni = 0; ni < 4; ni++) {
      int cl = wn * 64 + ni * 16 + l16;
      float bv = bb[n0 + cl];
      #pragma unroll
      for (int r = 0; r < 4; r++) {
        float w = wrow[rbase0 + rl + r];
        Hs[rl + r][cl] = f2bf(w * (acc[mi][ni][r] + bv));
      }
    }
  }
  wg_barrier();
  int row16 = tid >> 4, colg = (tid & 15) * 8;
  #pragma unroll
  for (int ps = 0; ps < 8; ps++) {
    int row = ps * 16 + row16;
    u32x4 v = *(const u32x4*)&Hs[row][colg];
    *(u32x4*)(partial + (size_t)(rbase0 + row) * DM + n0 + colg) = v;
  }
}

// ---------------- combine ----------------
__global__ __launch_bounds__(256) void combine_kernel(const short* __restrict__ partial,
                                                      const int* __restrict__ arow,
                                                      float* __restrict__ out) {
  int gid = blockIdx.x * 256 + threadIdx.x;
  int t = gid >> 6, c0 = (gid & 63) << 3;
  const int* ar = arow + t * 4;
  float o[8];
  #pragma unroll
  for (int k = 0; k < 8; k++) o[k] = 0.f;
  #pragma unroll
  for (int s = 0; s < 4; s++) {
    int a = ar[s];
    if (a >= 0) {
      union { u32x4 v; short s16[8]; } buf;
      buf.v = *(const u32x4*)(partial + (size_t)a * DM + c0);
      #pragma unroll
      for (int k = 0; k < 8; k++) o[k] += bf2f(buf.s16[k]);
    }
  }
  float* op = out + (size_t)t * DM + c0;
  *(f32x4*)op = (f32x4){o[0], o[1], o[2], o[3]};
  *(f32x4*)(op + 4) = (f32x4){o[4], o[5], o[6], o[7]};
}

extern "C" void kernel_launch(void* const* d_in, const int* in_sizes, int n_in,
                              void* d_out, int out_size, void* d_ws, size_t ws_size,
                              hipStream_t stream) {
  const float* x  = (const float*)d_in[0];
  const float* rw = (const float*)d_in[1];
  const float* W1 = (const float*)d_in[2];
  const float* b1 = (const float*)d_in[3];
  const float* W2 = (const float*)d_in[4];
  const float* b2 = (const float*)d_in[5];
  float* out = (float*)d_out;

  char* base_p = (char*)d_ws; char* p = base_p;
  auto carve = [&](size_t bytes) { char* r = p; p += (bytes + 255) & ~(size_t)255; return r; };
  short* xb    = (short*)carve((size_t)NTOK * DM * 2);
  short* w1b   = (short*)carve((size_t)NE * DM * DFF * 2);  // [e][DFF][DM]
  short* w2b   = (short*)carve((size_t)NE * DFF * DM * 2);  // [e][DM][DFF]
  int*   sel_e = (int*)carve((size_t)NTOK * 4 * 4);
  float* sel_w = (float*)carve((size_t)NTOK * 4 * 4);
  float* part  = (float*)carve(256 * 16 * 4);
  int*   meta  = (int*)carve(64 * 4);
  int*   arow  = (int*)carve((size_t)NTOK * 4 * 4);
  int*   mlist = (int*)carve((size_t)ROWCAP * 4);
  float* wrow  = (float*)carve((size_t)ROWCAP * 4);
  short* Hbig  = (short*)carve((size_t)ROWCAP * DFF * 2);
  short* partial = (short*)carve((size_t)ROWCAP * DM * 2);

  cvtT2_kernel<<<dim3(512, NE * 2), 256, 0, stream>>>(W1, w1b, W2, w2b);
  router_kernel<<<256, 256, 0, stream>>>(x, rw, xb, sel_e, sel_w, part);
  prep_kernel<<<1, 256, 0, stream>>>(part, out + (size_t)NTOK * DM, meta);
  build_kernel<<<256, 256, 0, stream>>>(sel_e, sel_w, meta, mlist, wrow, arow);
  gemm1_sp<<<dim3(DFF / 128, NE * 64), 256, 0, stream>>>(xb, w1b, b1, Hbig, mlist, meta);
  gemm2_sp<<<dim3(DM / 128, NE * 64), 256, 0, stream>>>(Hbig, w2b, b2, partial, wrow, meta);
  combine_kernel<<<NTOK * DM / 8 / 256, 256, 0, stream>>>(partial, arow, out);
}